// Round 2
// baseline (505.550 us; speedup 1.0000x reference)
//
#include <hip/hip_runtime.h>

typedef unsigned int u32;
typedef unsigned short u16;
typedef __attribute__((ext_vector_type(4))) float f32x4;
typedef __attribute__((ext_vector_type(8))) short bf16x8;
typedef __attribute__((ext_vector_type(4))) u32 u32x4;

__device__ __forceinline__ u16 f2bf(float f) {
  u32 u = __builtin_bit_cast(u32, f);
  u = u + 0x7FFFu + ((u >> 16) & 1u);
  return (u16)(u >> 16);
}
__device__ __forceinline__ u32 pack2(float a, float b) {
  return (u32)f2bf(a) | ((u32)f2bf(b) << 16);
}

#define MFMA(a, b, c) __builtin_amdgcn_mfma_f32_16x16x32_bf16((a), (b), (c), 0, 0, 0)

// LDS fragment read: row-major buffer, XOR-swizzled within 128B window.
__device__ __forceinline__ bf16x8 lds_frag(const char* buf, int rowBytes, int row, int kByte) {
  return *(const bf16x8*)(buf + row * rowBytes + (kByte ^ ((row & 7) << 4)));
}

// window/token -> flat token index in [B,32,32,32] (C-contiguous per token)
__device__ __forceinline__ int tok_global(int blk, int t) {
  int b = blk >> 9, r = blk & 511;
  int wd = r >> 6, wh = (r >> 3) & 7, ww = r & 7;
  int d = wd * 4 + (t >> 4);
  int h = wh * 4 + ((t >> 2) & 3);
  int w = ww * 4 + (t & 3);
  return ((b * 32 + d) * 32 + h) * 32 + w;
}

// Transpose + bf16-convert weights into workspace: WTq [1536][512], WTp [512][512]
__global__ void prep_weights(const float* __restrict__ wq, const float* __restrict__ wp,
                             u16* __restrict__ wtq, u16* __restrict__ wtp) {
  int idx = blockIdx.x * 512 + threadIdx.x;
  if (idx < 512 * 1536) {
    int i = idx / 1536, o = idx % 1536;     // coalesced read of W_qkv[i][o]
    wtq[o * 512 + i] = f2bf(wq[idx]);
  } else {
    int j = idx - 512 * 1536;
    int i = j >> 9, o = j & 511;
    wtp[o * 512 + i] = f2bf(wp[j]);
  }
}

__global__ __launch_bounds__(512, 2) void fused_win_attn(
    const float* __restrict__ x, const float* __restrict__ bq, const float* __restrict__ bp,
    const u16* __restrict__ wtq, const u16* __restrict__ wtp, float* __restrict__ out) {
  // LDS: [0,16K) x-chunk [64][128] bf16 swizzled; [16K,144K) per-wave bufA(8K)+bufB(8K)
  // After PV, [0,64K) is reused as O [64][512] bf16 swizzled.
  __shared__ char smem[147456];
  char* xc = smem;
  const int tid = threadIdx.x;
  const int wv = tid >> 6;   // wave id == head id
  const int l  = tid & 63;
  const int lr = l & 15;
  const int g  = l >> 4;
  const int blk = blockIdx.x;
  char* bufA = smem + 16384 + wv * 16384;  // Q then P   [64][64] bf16 swz
  char* bufB = bufA + 8192;                // K then V^T [64][64] bf16 swz

  // staging: thread loads 16 ch of one token per chunk
  const int st = tid >> 3, seg = tid & 7;
  const float* xsrc = x + (size_t)tok_global(blk, st) * 512 + seg * 16;
  const int stw = (st & 7) << 4;
  char* xw0 = xc + st * 256 + ((seg * 32) ^ stw);
  char* xw1 = xc + st * 256 + ((seg * 32 + 16) ^ stw);

  // per-lane weight base pointers (A/B-frag row = wv*64 + i*16 + lr, k-offset g*8)
  const u16* wq_lane = wtq + (size_t)(wv * 64 + lr) * 512 + g * 8;
  const u16* wk_lane = wq_lane + (size_t)512 * 512;
  const u16* wv_lane = wq_lane + (size_t)1024 * 512;
  const u16* wp_lane = wtp + (size_t)(wv * 64 + lr) * 512 + g * 8;

  // ======== Merged pass: Q,K (M=och,N=t) and V (M=t,N=d) in ONE x traversal ========
  f32x4 qacc[4][4], kacc[4][4], vacc[4][4];
#pragma unroll
  for (int i = 0; i < 4; ++i)
#pragma unroll
    for (int j = 0; j < 4; ++j) {
      qacc[i][j] = (f32x4)0.f; kacc[i][j] = (f32x4)0.f; vacc[i][j] = (f32x4)0.f;
    }

  for (int c = 0; c < 4; ++c) {
    __syncthreads();
    {
      const float4* s4 = (const float4*)(xsrc + c * 128);
      float4 f0 = s4[0], f1 = s4[1], f2 = s4[2], f3 = s4[3];
      u32x4 w0 = {pack2(f0.x, f0.y), pack2(f0.z, f0.w), pack2(f1.x, f1.y), pack2(f1.z, f1.w)};
      u32x4 w1 = {pack2(f2.x, f2.y), pack2(f2.z, f2.w), pack2(f3.x, f3.y), pack2(f3.z, f3.w)};
      *(u32x4*)xw0 = w0;
      *(u32x4*)xw1 = w1;
    }
    __syncthreads();
#pragma unroll
    for (int kk = 0; kk < 4; ++kk) {
      const int kByte = kk * 64 + g * 16;
      const int kofs = c * 128 + kk * 32;
      // batched loads: x frags (LDS) + weight frags (global/L2)
      bf16x8 bx[4], wqf[4], wkf[4], wvf[4];
#pragma unroll
      for (int j = 0; j < 4; ++j) bx[j] = lds_frag(xc, 256, j * 16 + lr, kByte);
#pragma unroll
      for (int i = 0; i < 4; ++i) wqf[i] = *(const bf16x8*)(wq_lane + kofs + i * 8192);
#pragma unroll
      for (int i = 0; i < 4; ++i) wkf[i] = *(const bf16x8*)(wk_lane + kofs + i * 8192);
#pragma unroll
      for (int i = 0; i < 4; ++i) wvf[i] = *(const bf16x8*)(wv_lane + kofs + i * 8192);
#pragma unroll
      for (int i = 0; i < 4; ++i)
#pragma unroll
        for (int j = 0; j < 4; ++j) qacc[i][j] = MFMA(wqf[i], bx[j], qacc[i][j]);
#pragma unroll
      for (int i = 0; i < 4; ++i)
#pragma unroll
        for (int j = 0; j < 4; ++j) kacc[i][j] = MFMA(wkf[i], bx[j], kacc[i][j]);
#pragma unroll
      for (int ti = 0; ti < 4; ++ti)
#pragma unroll
        for (int ni = 0; ni < 4; ++ni) vacc[ti][ni] = MFMA(bx[ti], wvf[ni], vacc[ti][ni]);
    }
  }

  // ---- Q,K epilogues: +bias, bf16, Q -> bufA, K -> bufB (layout [t][d], d-pairs packed) ----
#pragma unroll
  for (int i = 0; i < 4; ++i) {
    const int dbase = i * 16 + g * 4;
    const int ochq = wv * 64 + dbase;
    float qb0 = bq[ochq], qb1 = bq[ochq + 1], qb2 = bq[ochq + 2], qb3 = bq[ochq + 3];
    float kb0 = bq[512 + ochq], kb1 = bq[512 + ochq + 1], kb2 = bq[512 + ochq + 2], kb3 = bq[512 + ochq + 3];
#pragma unroll
    for (int j = 0; j < 4; ++j) {
      int t = j * 16 + lr;
      int swz = (t & 7) << 4;
      f32x4 vq = qacc[i][j], vk = kacc[i][j];
      *(u32*)(bufA + t * 128 + ((dbase * 2) ^ swz))     = pack2(vq[0] + qb0, vq[1] + qb1);
      *(u32*)(bufA + t * 128 + ((dbase * 2 + 4) ^ swz)) = pack2(vq[2] + qb2, vq[3] + qb3);
      *(u32*)(bufB + t * 128 + ((dbase * 2) ^ swz))     = pack2(vk[0] + kb0, vk[1] + kb1);
      *(u32*)(bufB + t * 128 + ((dbase * 2 + 4) ^ swz)) = pack2(vk[2] + kb2, vk[3] + kb3);
    }
  }
  asm volatile("s_waitcnt lgkmcnt(0)" ::: "memory");

  // ======== S = Q K^T ========
  f32x4 sf[4][4];
#pragma unroll
  for (int i = 0; i < 4; ++i)
#pragma unroll
    for (int j = 0; j < 4; ++j) sf[i][j] = (f32x4)0.f;
#pragma unroll
  for (int kk = 0; kk < 2; ++kk) {
    const int kByte = kk * 64 + g * 16;
    bf16x8 qa[4], kb[4];
#pragma unroll
    for (int i = 0; i < 4; ++i) qa[i] = lds_frag(bufA, 128, i * 16 + lr, kByte);
#pragma unroll
    for (int j = 0; j < 4; ++j) kb[j] = lds_frag(bufB, 128, j * 16 + lr, kByte);
#pragma unroll
    for (int i = 0; i < 4; ++i)
#pragma unroll
      for (int j = 0; j < 4; ++j) sf[i][j] = MFMA(qa[i], kb[j], sf[i][j]);
  }

  // ---- V epilogue: write V^T into bufB (K dead after S reads; DS is in-order per wave) ----
#pragma unroll
  for (int ti = 0; ti < 4; ++ti)
#pragma unroll
    for (int ni = 0; ni < 4; ++ni) {
      int d = ni * 16 + lr;
      float bb = bq[1024 + wv * 64 + d];
      f32x4 v = vacc[ti][ni];
      int s0 = ti * 16 + g * 4;
      int swz = (d & 7) << 4;
      *(u32*)(bufB + d * 128 + ((s0 * 2) ^ swz))     = pack2(v[0] + bb, v[1] + bb);
      *(u32*)(bufB + d * 128 + ((s0 * 2 + 4) ^ swz)) = pack2(v[2] + bb, v[3] + bb);
    }

  // ---- scale + clip + softmax (ILP form: 16 independent rows, level-major shuffles) ----
#pragma unroll
  for (int i = 0; i < 4; ++i)
#pragma unroll
    for (int j = 0; j < 4; ++j)
#pragma unroll
      for (int r = 0; r < 4; ++r) {
        float v = sf[i][j][r] * 0.125f;
        sf[i][j][r] = fminf(fmaxf(v, -10000.f), 10000.f);
      }
  float mx[4][4], sm[4][4];
#pragma unroll
  for (int ti = 0; ti < 4; ++ti)
#pragma unroll
    for (int r = 0; r < 4; ++r)
      mx[ti][r] = fmaxf(fmaxf(sf[ti][0][r], sf[ti][1][r]), fmaxf(sf[ti][2][r], sf[ti][3][r]));
#pragma unroll
  for (int lvl = 1; lvl <= 8; lvl <<= 1)
#pragma unroll
    for (int ti = 0; ti < 4; ++ti)
#pragma unroll
      for (int r = 0; r < 4; ++r) mx[ti][r] = fmaxf(mx[ti][r], __shfl_xor(mx[ti][r], lvl));
#pragma unroll
  for (int ti = 0; ti < 4; ++ti)
#pragma unroll
    for (int r = 0; r < 4; ++r) {
      float s0 = 0.f;
#pragma unroll
      for (int sj = 0; sj < 4; ++sj) {
        float p = __expf(sf[ti][sj][r] - mx[ti][r]);
        sf[ti][sj][r] = p;
        s0 += p;
      }
      sm[ti][r] = s0;
    }
#pragma unroll
  for (int lvl = 1; lvl <= 8; lvl <<= 1)
#pragma unroll
    for (int ti = 0; ti < 4; ++ti)
#pragma unroll
      for (int r = 0; r < 4; ++r) sm[ti][r] += __shfl_xor(sm[ti][r], lvl);
#pragma unroll
  for (int ti = 0; ti < 4; ++ti)
#pragma unroll
    for (int r = 0; r < 4; ++r) {
      float inv = 1.f / sm[ti][r];
#pragma unroll
      for (int sj = 0; sj < 4; ++sj) sf[ti][sj][r] *= inv;
    }
  // write P into bufA (Q dead): layout [t][s]
#pragma unroll
  for (int ti = 0; ti < 4; ++ti)
#pragma unroll
    for (int sj = 0; sj < 4; ++sj)
#pragma unroll
      for (int r = 0; r < 4; ++r) {
        int t = ti * 16 + g * 4 + r;
        int s = sj * 16 + lr;
        *(u16*)(bufA + t * 128 + ((s * 2) ^ ((t & 7) << 4))) = f2bf(sf[ti][sj][r]);
      }
  asm volatile("s_waitcnt lgkmcnt(0)" ::: "memory");

  // ======== O^T = V^T @ P^T (M=d, N=t, K=s) ========
  f32x4 of[4][4];
#pragma unroll
  for (int i = 0; i < 4; ++i)
#pragma unroll
    for (int j = 0; j < 4; ++j) of[i][j] = (f32x4)0.f;
#pragma unroll
  for (int kk = 0; kk < 2; ++kk) {
    const int kByte = kk * 64 + g * 16;
    bf16x8 va[4], pb[4];
#pragma unroll
    for (int di = 0; di < 4; ++di) va[di] = lds_frag(bufB, 128, di * 16 + lr, kByte);
#pragma unroll
    for (int tj = 0; tj < 4; ++tj) pb[tj] = lds_frag(bufA, 128, tj * 16 + lr, kByte);
#pragma unroll
    for (int di = 0; di < 4; ++di)
#pragma unroll
      for (int tj = 0; tj < 4; ++tj) of[di][tj] = MFMA(va[di], pb[tj], of[di][tj]);
  }
  __syncthreads();  // everyone done with x-chunk + all per-wave bufs
  // write O (concat heads) into smem[0..64K): layout [t][512ch] bf16 swizzled
  char* olds = smem;
#pragma unroll
  for (int di = 0; di < 4; ++di)
#pragma unroll
    for (int tj = 0; tj < 4; ++tj) {
      int t = tj * 16 + lr;
      int cb = wv * 128 + di * 32 + g * 8;
      int swz = (t & 7) << 4;
      f32x4 v = of[di][tj];
      *(u32*)(olds + t * 1024 + ((cb) ^ swz))     = pack2(v[0], v[1]);
      *(u32*)(olds + t * 1024 + ((cb + 4) ^ swz)) = pack2(v[2], v[3]);
    }
  __syncthreads();

  // ======== Y = O @ Wproj (M=och, N=t, K=ch) ========
  f32x4 y[4][4];
#pragma unroll
  for (int i = 0; i < 4; ++i)
#pragma unroll
    for (int j = 0; j < 4; ++j) y[i][j] = (f32x4)0.f;
#pragma unroll
  for (int kk = 0; kk < 16; ++kk) {
    const int kByte = kk * 64 + g * 16;
    bf16x8 ob[4], wa[4];
#pragma unroll
    for (int tj = 0; tj < 4; ++tj) ob[tj] = lds_frag(olds, 1024, tj * 16 + lr, kByte);
#pragma unroll
    for (int mi = 0; mi < 4; ++mi) wa[mi] = *(const bf16x8*)(wp_lane + kk * 32 + mi * 8192);
#pragma unroll
    for (int mi = 0; mi < 4; ++mi)
#pragma unroll
      for (int tj = 0; tj < 4; ++tj) y[mi][tj] = MFMA(wa[mi], ob[tj], y[mi][tj]);
  }
  // epilogue: +bias, coalesced float4 scatter to output
#pragma unroll
  for (int mi = 0; mi < 4; ++mi) {
    const int och = wv * 64 + mi * 16 + g * 4;
    float b0 = bp[och], b1 = bp[och + 1], b2 = bp[och + 2], b3 = bp[och + 3];
#pragma unroll
    for (int tj = 0; tj < 4; ++tj) {
      int t = tj * 16 + lr;
      f32x4 v = y[mi][tj];
      float4 o;
      o.x = v[0] + b0; o.y = v[1] + b1; o.z = v[2] + b2; o.w = v[3] + b3;
      *(float4*)(out + (size_t)tok_global(blk, t) * 512 + och) = o;
    }
  }
}

extern "C" void kernel_launch(void* const* d_in, const int* in_sizes, int n_in,
                              void* d_out, int out_size, void* d_ws, size_t ws_size,
                              hipStream_t stream) {
  const float* x  = (const float*)d_in[0];
  const float* wq = (const float*)d_in[1];
  const float* bq = (const float*)d_in[2];
  const float* wp = (const float*)d_in[3];
  const float* bp = (const float*)d_in[4];
  float* out = (float*)d_out;
  u16* wtq = (u16*)d_ws;            // [1536][512] bf16
  u16* wtp = wtq + 512 * 1536;      // [512][512]  bf16

  prep_weights<<<2048, 512, 0, stream>>>(wq, wp, wtq, wtp);
  fused_win_attn<<<1024, 512, 0, stream>>>(x, bq, bp, wtq, wtp, out);
}

// Round 3
// 311.304 us; speedup vs baseline: 1.6240x; 1.6240x over previous
//
#include <hip/hip_runtime.h>

typedef unsigned int u32;
typedef unsigned short u16;
typedef __attribute__((ext_vector_type(4))) float f32x4;
typedef __attribute__((ext_vector_type(8))) short bf16x8;
typedef __attribute__((ext_vector_type(4))) u32 u32x4;

__device__ __forceinline__ u16 f2bf(float f) {
  u32 u = __builtin_bit_cast(u32, f);
  u = u + 0x7FFFu + ((u >> 16) & 1u);
  return (u16)(u >> 16);
}
__device__ __forceinline__ u32 pack2(float a, float b) {
  return (u32)f2bf(a) | ((u32)f2bf(b) << 16);
}
// Pack two C-frags (f32x4 each) into one A/B-frag under the consistent
// k-permutation sigma(8g+p) = 16*(p>>2) + g*4 + (p&3) (+32*kb outside).
__device__ __forceinline__ bf16x8 pack8(f32x4 a, f32x4 b) {
  union { u32 w[4]; bf16x8 v; } u;
  u.w[0] = pack2(a[0], a[1]); u.w[1] = pack2(a[2], a[3]);
  u.w[2] = pack2(b[0], b[1]); u.w[3] = pack2(b[2], b[3]);
  return u.v;
}

#define MFMA(a, b, c) __builtin_amdgcn_mfma_f32_16x16x32_bf16((a), (b), (c), 0, 0, 0)

// LDS fragment read: row-major buffer, XOR-swizzled within 128B window.
__device__ __forceinline__ bf16x8 lds_frag(const char* buf, int rowBytes, int row, int kByte) {
  return *(const bf16x8*)(buf + row * rowBytes + (kByte ^ ((row & 7) << 4)));
}

// window/token -> flat token index in [B,32,32,32] (C-contiguous per token)
__device__ __forceinline__ int tok_global(int blk, int t) {
  int b = blk >> 9, r = blk & 511;
  int wd = r >> 6, wh = (r >> 3) & 7, ww = r & 7;
  int d = wd * 4 + (t >> 4);
  int h = wh * 4 + ((t >> 2) & 3);
  int w = ww * 4 + (t & 3);
  return ((b * 32 + d) * 32 + h) * 32 + w;
}

// Transpose + bf16-convert weights into workspace: WTq [1536][512], WTp [512][512]
__global__ void prep_weights(const float* __restrict__ wq, const float* __restrict__ wp,
                             u16* __restrict__ wtq, u16* __restrict__ wtp) {
  int idx = blockIdx.x * 512 + threadIdx.x;
  if (idx < 512 * 1536) {
    int i = idx / 1536, o = idx % 1536;     // coalesced read of W_qkv[i][o]
    wtq[o * 512 + i] = f2bf(wq[idx]);
  } else {
    int j = idx - 512 * 1536;
    int i = j >> 9, o = j & 511;
    wtp[o * 512 + i] = f2bf(wp[j]);
  }
}

__global__ __launch_bounds__(512, 2) void fused_win_attn(
    const float* __restrict__ x, const float* __restrict__ bq, const float* __restrict__ bp,
    const u16* __restrict__ wtq, const u16* __restrict__ wtp, float* __restrict__ out) {
  // LDS: x [64 tok][512 ch] bf16, XOR-swizzled; reused as O (same layout) after V pass.
  __shared__ char smem[65536];
  const int tid = threadIdx.x;
  const int wv = tid >> 6;   // wave id == head id
  const int l  = tid & 63;
  const int lr = l & 15;
  const int g  = l >> 4;
  const int blk = blockIdx.x;

  // ---- stage x -> LDS bf16 (once; 1 barrier) ----
  {
    const int st = tid >> 3, seg = tid & 7;       // token row, 64-ch segment
    const float* xs = x + (size_t)tok_global(blk, st) * 512 + seg * 64;
    char* dst = smem + st * 1024;
    const int swz = (st & 7) << 4;
    float4 f[16];
#pragma unroll
    for (int i = 0; i < 16; ++i) f[i] = ((const float4*)xs)[i];
#pragma unroll
    for (int i = 0; i < 8; ++i) {
      u32x4 w = {pack2(f[2 * i].x, f[2 * i].y),     pack2(f[2 * i].z, f[2 * i].w),
                 pack2(f[2 * i + 1].x, f[2 * i + 1].y), pack2(f[2 * i + 1].z, f[2 * i + 1].w)};
      *(u32x4*)(dst + ((seg * 128 + i * 16) ^ swz)) = w;
    }
  }
  __syncthreads();

  // per-lane weight base pointers (frag row = wv*64 + i*16 + lr, k-offset g*8)
  const u16* wq_lane = wtq + (size_t)(wv * 64 + lr) * 512 + g * 8;
  const u16* wk_lane = wq_lane + (size_t)512 * 512;
  const u16* wv_lane = wq_lane + (size_t)1024 * 512;
  const u16* wp_lane = wtp + (size_t)(wv * 64 + lr) * 512 + g * 8;

  // ======== QK pass: Q,K [d=64][t=64] accs (M=och, N=t, K=ch 512) ========
  f32x4 qacc[4][4], kacc[4][4];
#pragma unroll
  for (int i = 0; i < 4; ++i)
#pragma unroll
    for (int j = 0; j < 4; ++j) { qacc[i][j] = (f32x4)0.f; kacc[i][j] = (f32x4)0.f; }
#pragma unroll 4
  for (int ks = 0; ks < 16; ++ks) {
    const int kByte = ks * 64 + g * 16;
    const int kel = ks * 32;
    bf16x8 bx[4], wqf[4], wkf[4];
#pragma unroll
    for (int j = 0; j < 4; ++j) bx[j] = lds_frag(smem, 1024, j * 16 + lr, kByte);
#pragma unroll
    for (int i = 0; i < 4; ++i) wqf[i] = *(const bf16x8*)(wq_lane + kel + i * 8192);
#pragma unroll
    for (int i = 0; i < 4; ++i) wkf[i] = *(const bf16x8*)(wk_lane + kel + i * 8192);
#pragma unroll
    for (int i = 0; i < 4; ++i)
#pragma unroll
      for (int j = 0; j < 4; ++j) qacc[i][j] = MFMA(wqf[i], bx[j], qacc[i][j]);
#pragma unroll
    for (int i = 0; i < 4; ++i)
#pragma unroll
      for (int j = 0; j < 4; ++j) kacc[i][j] = MFMA(wkf[i], bx[j], kacc[i][j]);
  }
  // +bias, pack to frags in registers (no LDS round-trip).
  bf16x8 qp[4][2], ka[4][2];
#pragma unroll
  for (int i = 0; i < 4; ++i) {
    const int och = wv * 64 + i * 16 + g * 4;
    f32x4 qb = {bq[och], bq[och + 1], bq[och + 2], bq[och + 3]};
    f32x4 kb = {bq[512 + och], bq[512 + och + 1], bq[512 + och + 2], bq[512 + och + 3]};
#pragma unroll
    for (int j = 0; j < 4; ++j) { qacc[i][j] += qb; kacc[i][j] += kb; }
  }
#pragma unroll
  for (int j = 0; j < 4; ++j)
#pragma unroll
    for (int kb = 0; kb < 2; ++kb) {
      qp[j][kb] = pack8(qacc[2 * kb][j], qacc[2 * kb + 1][j]);   // B-frag: col t, k=d
      ka[j][kb] = pack8(kacc[2 * kb][j], kacc[2 * kb + 1][j]);   // A-frag: row s, k=d
    }

  // ======== S^T = K^T-rows x Q (M=s, N=t, K=d=64): pure register MFMA ========
  f32x4 sacc[4][4];
#pragma unroll
  for (int m = 0; m < 4; ++m)
#pragma unroll
    for (int j = 0; j < 4; ++j) {
      f32x4 a = (f32x4)0.f;
      a = MFMA(ka[m][0], qp[j][0], a);
      sacc[m][j] = MFMA(ka[m][1], qp[j][1], a);
    }

  // ---- scale + clip + softmax over s (16 local + xor16 + xor32) ----
#pragma unroll
  for (int m = 0; m < 4; ++m)
#pragma unroll
    for (int j = 0; j < 4; ++j)
#pragma unroll
      for (int r = 0; r < 4; ++r) {
        float v = sacc[m][j][r] * 0.125f;
        sacc[m][j][r] = fminf(fmaxf(v, -10000.f), 10000.f);
      }
  float mx[4], sm[4];
#pragma unroll
  for (int j = 0; j < 4; ++j) {
    float a0 = fmaxf(fmaxf(sacc[0][j][0], sacc[0][j][1]), fmaxf(sacc[0][j][2], sacc[0][j][3]));
    float a1 = fmaxf(fmaxf(sacc[1][j][0], sacc[1][j][1]), fmaxf(sacc[1][j][2], sacc[1][j][3]));
    float a2 = fmaxf(fmaxf(sacc[2][j][0], sacc[2][j][1]), fmaxf(sacc[2][j][2], sacc[2][j][3]));
    float a3 = fmaxf(fmaxf(sacc[3][j][0], sacc[3][j][1]), fmaxf(sacc[3][j][2], sacc[3][j][3]));
    mx[j] = fmaxf(fmaxf(a0, a1), fmaxf(a2, a3));
  }
#pragma unroll
  for (int j = 0; j < 4; ++j) mx[j] = fmaxf(mx[j], __shfl_xor(mx[j], 16));
#pragma unroll
  for (int j = 0; j < 4; ++j) mx[j] = fmaxf(mx[j], __shfl_xor(mx[j], 32));
#pragma unroll
  for (int j = 0; j < 4; ++j) {
    float s0 = 0.f;
#pragma unroll
    for (int m = 0; m < 4; ++m)
#pragma unroll
      for (int r = 0; r < 4; ++r) {
        float p = __expf(sacc[m][j][r] - mx[j]);
        sacc[m][j][r] = p;
        s0 += p;
      }
    sm[j] = s0;
  }
#pragma unroll
  for (int j = 0; j < 4; ++j) sm[j] += __shfl_xor(sm[j], 16);
#pragma unroll
  for (int j = 0; j < 4; ++j) sm[j] += __shfl_xor(sm[j], 32);
  bf16x8 pb[4][2];
#pragma unroll
  for (int j = 0; j < 4; ++j) {
    float inv = 1.f / sm[j];
#pragma unroll
    for (int kb = 0; kb < 2; ++kb)
      pb[j][kb] = pack8(sacc[2 * kb][j] * inv, sacc[2 * kb + 1][j] * inv);  // B-frag: col t, k=s
  }

  // ======== V pass: V [s=64][d=64] accs (M=t(=s), N=d, K=ch 512) ========
  f32x4 vacc[4][4];
#pragma unroll
  for (int i = 0; i < 4; ++i)
#pragma unroll
    for (int j = 0; j < 4; ++j) vacc[i][j] = (f32x4)0.f;
#pragma unroll 4
  for (int ks = 0; ks < 16; ++ks) {
    const int kByte = ks * 64 + g * 16;
    const int kel = ks * 32;
    bf16x8 bx[4], wvf[4];
#pragma unroll
    for (int ti = 0; ti < 4; ++ti) bx[ti] = lds_frag(smem, 1024, ti * 16 + lr, kByte);
#pragma unroll
    for (int ni = 0; ni < 4; ++ni) wvf[ni] = *(const bf16x8*)(wv_lane + kel + ni * 8192);
#pragma unroll
    for (int ti = 0; ti < 4; ++ti)
#pragma unroll
      for (int ni = 0; ni < 4; ++ni) vacc[ti][ni] = MFMA(bx[ti], wvf[ni], vacc[ti][ni]);
  }
  // +bias (d = col = lane&15 + 16ni), pack A-frags (row d, k=s)
  bf16x8 va[4][2];
#pragma unroll
  for (int ni = 0; ni < 4; ++ni) {
    float bv = bq[1024 + wv * 64 + ni * 16 + lr];
#pragma unroll
    for (int ti = 0; ti < 4; ++ti) vacc[ti][ni] += (f32x4)bv;
#pragma unroll
    for (int kb = 0; kb < 2; ++kb)
      va[ni][kb] = pack8(vacc[2 * kb][ni], vacc[2 * kb + 1][ni]);
  }

  // ======== O^T = V^T x P^T (M=d, N=t, K=s=64): pure register MFMA ========
  f32x4 oacc[4][4];
#pragma unroll
  for (int ni = 0; ni < 4; ++ni)
#pragma unroll
    for (int j = 0; j < 4; ++j) {
      f32x4 a = (f32x4)0.f;
      a = MFMA(va[ni][0], pb[j][0], a);
      oacc[ni][j] = MFMA(va[ni][1], pb[j][1], a);
    }

  // ---- O (concat heads) -> LDS [t][512] bf16 (x is dead) ----
  __syncthreads();
#pragma unroll
  for (int ni = 0; ni < 4; ++ni)
#pragma unroll
    for (int j = 0; j < 4; ++j) {
      int t = j * 16 + lr;
      int cb = (wv * 64 + ni * 16 + g * 4) * 2;
      int swz = (t & 7) << 4;
      f32x4 v = oacc[ni][j];
      *(u32*)(smem + t * 1024 + (cb ^ swz))       = pack2(v[0], v[1]);
      *(u32*)(smem + t * 1024 + ((cb + 4) ^ swz)) = pack2(v[2], v[3]);
    }
  __syncthreads();

  // ======== Y = O @ Wproj (M=och, N=t, K=ch 512) ========
  f32x4 y[4][4];
#pragma unroll
  for (int i = 0; i < 4; ++i)
#pragma unroll
    for (int j = 0; j < 4; ++j) y[i][j] = (f32x4)0.f;
#pragma unroll 4
  for (int ks = 0; ks < 16; ++ks) {
    const int kByte = ks * 64 + g * 16;
    const int kel = ks * 32;
    bf16x8 ob[4], wa[4];
#pragma unroll
    for (int tj = 0; tj < 4; ++tj) ob[tj] = lds_frag(smem, 1024, tj * 16 + lr, kByte);
#pragma unroll
    for (int mi = 0; mi < 4; ++mi) wa[mi] = *(const bf16x8*)(wp_lane + kel + mi * 8192);
#pragma unroll
    for (int mi = 0; mi < 4; ++mi)
#pragma unroll
      for (int tj = 0; tj < 4; ++tj) y[mi][tj] = MFMA(wa[mi], ob[tj], y[mi][tj]);
  }
  // epilogue: +bias, coalesced float4 scatter to output
#pragma unroll
  for (int mi = 0; mi < 4; ++mi) {
    const int och = wv * 64 + mi * 16 + g * 4;
    float b0 = bp[och], b1 = bp[och + 1], b2 = bp[och + 2], b3 = bp[och + 3];
#pragma unroll
    for (int tj = 0; tj < 4; ++tj) {
      int t = tj * 16 + lr;
      f32x4 v = y[mi][tj];
      float4 o;
      o.x = v[0] + b0; o.y = v[1] + b1; o.z = v[2] + b2; o.w = v[3] + b3;
      *(float4*)(out + (size_t)tok_global(blk, t) * 512 + och) = o;
    }
  }
}

extern "C" void kernel_launch(void* const* d_in, const int* in_sizes, int n_in,
                              void* d_out, int out_size, void* d_ws, size_t ws_size,
                              hipStream_t stream) {
  const float* x  = (const float*)d_in[0];
  const float* wq = (const float*)d_in[1];
  const float* bq = (const float*)d_in[2];
  const float* wp = (const float*)d_in[3];
  const float* bp = (const float*)d_in[4];
  float* out = (float*)d_out;
  u16* wtq = (u16*)d_ws;            // [1536][512] bf16
  u16* wtp = wtq + 512 * 1536;      // [512][512]  bf16

  prep_weights<<<2048, 512, 0, stream>>>(wq, wp, wtq, wtp);
  fused_win_attn<<<1024, 512, 0, stream>>>(x, bq, bp, wtq, wtp, out);
}